// Round 7
// baseline (199.267 us; speedup 1.0000x reference)
//
#include <hip/hip_runtime.h>

typedef unsigned short u16;
typedef __bf16 bf16x8 __attribute__((ext_vector_type(8)));
typedef float f32x4 __attribute__((ext_vector_type(4)));

#define B_ 4
#define T_ 2048
#define C_ 512
#define H_ 8
#define D_ 64

// ---------- helpers ----------
__device__ __forceinline__ u16 f2bf(float f) {
  unsigned u = __float_as_uint(f);
  unsigned r = (u + 0x7FFFu + ((u >> 16) & 1u)) >> 16;
  return (u16)r;
}
__device__ __forceinline__ float bf2f(unsigned h) {
  return __uint_as_float(h << 16);
}
__device__ __forceinline__ void gload16(const u16* g, u16* l) {
  __builtin_amdgcn_global_load_lds(
      (const __attribute__((address_space(1))) unsigned int*)g,
      (__attribute__((address_space(3))) unsigned int*)l, 16, 0, 0);
}

// ---------- cast kernels ----------
__global__ void cast4_kernel(const float* __restrict__ in, u16* __restrict__ out) {
  int i = blockIdx.x * blockDim.x + threadIdx.x;   // over float4s (exact grid)
  float4 v = ((const float4*)in)[i];
  unsigned lo = (unsigned)f2bf(v.x) | ((unsigned)f2bf(v.y) << 16);
  unsigned hi = (unsigned)f2bf(v.z) | ((unsigned)f2bf(v.w) << 16);
  ((uint2*)out)[i] = make_uint2(lo, hi);
}

__global__ void castT_kernel(const float* __restrict__ in, u16* __restrict__ outT,
                             int R, int Cc) {
  int i = blockIdx.x * blockDim.x + threadIdx.x;
  if (i >= R * Cc) return;
  int r = i / Cc, c = i - r * Cc;
  outT[c * R + r] = f2bf(in[i]);
}

// ---------- RoPE ----------
__global__ void rope_table_kernel(float* __restrict__ cosT, float* __restrict__ sinT) {
  int i = blockIdx.x * blockDim.x + threadIdx.x;   // 65536 = T*32 exact
  int t = i >> 5, p = i & 31;
  float theta = powf(10000.f, -(float)p / 32.f);
  float a = (float)t * theta;
  cosT[i] = cosf(a);
  sinT[i] = sinf(a);
}

__global__ void rope_kernel(u16* __restrict__ Qp, u16* __restrict__ Kp,
                            const float* __restrict__ cosT, const float* __restrict__ sinT) {
  int i = blockIdx.x * blockDim.x + threadIdx.x;   // 4,194,304 exact
  int p = i & 31;
  int t = (i >> 5) & 2047;
  int bh = (i >> 16) & 31;
  u16* base = (i >> 21) ? Kp : Qp;
  unsigned off = ((unsigned)(bh * 2048 + t)) * 64u + (unsigned)(p * 2);
  unsigned v = *(const unsigned*)&base[off];
  int ti = (t << 5) + p;
  float c = cosT[ti], s = sinT[ti];
  float x1 = bf2f(v & 0xFFFFu), x2 = bf2f(v >> 16);
  float o1 = x1 * c - x2 * s;
  float o2 = x1 * s + x2 * c;
  *(unsigned*)&base[off] = (unsigned)f2bf(o1) | ((unsigned)f2bf(o2) << 16);
}

// ---------- GEMM: C = A * B, B given transposed (BT is N x K), all bf16, fp32 acc ----------
// (unswizzled: 2-phase structure, T2 is regime-gated null here per m252)
// EPI 0: scatter epilogue -> Q, K (bf16 [BH,T,D]) and VT (bf16 [BH,D,T])
// EPI 1: plain fp32 store to Cout (M x N)
template <int EPI>
__global__ __launch_bounds__(256, 2)
void gemm_bt_kernel(const u16* __restrict__ A, const u16* __restrict__ BT,
                    int M, int N, int K, float* __restrict__ Cout,
                    u16* __restrict__ Qp, u16* __restrict__ Kp, u16* __restrict__ VTp) {
  __shared__ u16 As[128 * 64];
  __shared__ u16 Bs[128 * 64];
  const int tid = threadIdx.x;
  const int w = tid >> 6, l = tid & 63;
  const int m0 = blockIdx.x * 128, n0 = blockIdx.y * 128;
  const int wr = w >> 1, wc = w & 1;
  f32x4 acc[4][4] = {};

  const int srow = w * 32 + (l >> 3);  // +c*8
  const int scol = (l & 7) * 8;

  for (int k0 = 0; k0 < K; k0 += 64) {
#pragma unroll
    for (int c = 0; c < 4; ++c) {
      gload16(A + (m0 + srow + c * 8) * K + k0 + scol, &As[(w * 32 + c * 8) * 64]);
      gload16(BT + (n0 + srow + c * 8) * K + k0 + scol, &Bs[(w * 32 + c * 8) * 64]);
    }
    __syncthreads();
#pragma unroll
    for (int kk = 0; kk < 2; ++kk) {
      bf16x8 af[4], bfr[4];
#pragma unroll
      for (int i = 0; i < 4; ++i)
        af[i] = *(const bf16x8*)&As[(wr * 64 + i * 16 + (l & 15)) * 64 + kk * 32 + (l >> 4) * 8];
#pragma unroll
      for (int j = 0; j < 4; ++j)
        bfr[j] = *(const bf16x8*)&Bs[(wc * 64 + j * 16 + (l & 15)) * 64 + kk * 32 + (l >> 4) * 8];
#pragma unroll
      for (int i = 0; i < 4; ++i)
#pragma unroll
        for (int j = 0; j < 4; ++j)
          acc[i][j] = __builtin_amdgcn_mfma_f32_16x16x32_bf16(af[i], bfr[j], acc[i][j], 0, 0, 0);
    }
    __syncthreads();
  }

  const int mrow = wr * 64 + (l >> 4) * 4;
  const int ncol = wc * 64 + (l & 15);
  if (EPI == 1) {
#pragma unroll
    for (int i = 0; i < 4; ++i)
#pragma unroll
      for (int j = 0; j < 4; ++j)
#pragma unroll
        for (int r = 0; r < 4; ++r)
          Cout[(m0 + mrow + i * 16 + r) * N + (n0 + ncol + j * 16)] = acc[i][j][r];
  } else {
#pragma unroll
    for (int i = 0; i < 4; ++i) {
#pragma unroll
      for (int j = 0; j < 4; ++j) {
        int n = n0 + ncol + j * 16;
        int which = n >> 9;
        int hn = n & 511;
        int h = hn >> 6, d = hn & 63;
#pragma unroll
        for (int r = 0; r < 4; ++r) {
          int m = m0 + mrow + i * 16 + r;
          int b = m >> 11, t = m & 2047;
          int bh = b * 8 + h;
          u16 v = f2bf(acc[i][j][r]);
          if (which == 0)
            Qp[(bh * 2048 + t) * 64 + d] = v;
          else if (which == 1)
            Kp[(bh * 2048 + t) * 64 + d] = v;
          else
            VTp[(bh * 64 + d) * 2048 + t] = v;
        }
      }
    }
  }
}

// ---------- attention: per block one (b,h) and 64 q rows; 4 waves x 16 q rows ----------
// T2 XOR-swizzle on Ks/Vs/Ps: lds(row, col) holds data(row, col ^ ((row&7)<<3)).
// Staging achieves this with LINEAR lds dest + pre-swizzled GLOBAL source col
// (rule #21: source perm == read perm, both-sides involution).
__global__ __launch_bounds__(256, 2)
void attn_kernel(const u16* __restrict__ Qp, const u16* __restrict__ Kp,
                 const u16* __restrict__ VTp, u16* __restrict__ Yp) {
  __shared__ u16 Ks[64 * 64];   // [key][d], swizzled
  __shared__ u16 Vs[64 * 64];   // [d][key]  (V^T tile), swizzled
  __shared__ u16 Ps[4 * 16 * 64];  // swizzled
  const int tid = threadIdx.x;
  const int w = tid >> 6, l = tid & 63;
  const int qt = blockIdx.x, bh = blockIdx.y;
  const int b = bh >> 3, h = bh & 7;
  const int q0 = qt * 64;
  const u16* Qb = Qp + (bh * 2048 + q0) * 64;
  const u16* Kb = Kp + bh * 2048 * 64;
  const u16* Vb = VTp + bh * 64 * 2048;

  // hoist Q fragments (16 rows per wave, D=64 over 2 k-steps) — global, unswizzled
  bf16x8 qf[2];
  {
    int row = w * 16 + (l & 15);
#pragma unroll
    for (int kk = 0; kk < 2; ++kk)
      qf[kk] = *(const bf16x8*)&Qb[row * 64 + kk * 32 + (l >> 4) * 8];
  }
  f32x4 o[4] = {};
  float dsum[4] = {0.f, 0.f, 0.f, 0.f};

  const int srow = w * 16 + (l >> 3);                 // +c*8; (row&7) == l>>3
  const int scol = ((l & 7) ^ (l >> 3)) * 8;          // pre-swizzled source col
  const int rsw  = (l & 7) << 3;                      // read-side XOR (row&7 == l&7)

  for (int kt = 0; kt < 32; ++kt) {
#pragma unroll
    for (int c = 0; c < 2; ++c) {
      gload16(Kb + (kt * 64 + srow + c * 8) * 64 + scol, &Ks[(w * 16 + c * 8) * 64]);
      gload16(Vb + (srow + c * 8) * 2048 + kt * 64 + scol, &Vs[(w * 16 + c * 8) * 64]);
    }
    __syncthreads();

    // S = Q K^T for this wave's 16 q rows x 64 keys
#pragma unroll
    for (int nt = 0; nt < 4; ++nt) {
      f32x4 s = {0.f, 0.f, 0.f, 0.f};
#pragma unroll
      for (int kk = 0; kk < 2; ++kk) {
        bf16x8 kf = *(const bf16x8*)&Ks[(nt * 16 + (l & 15)) * 64 +
                                        ((kk * 32 + (l >> 4) * 8) ^ rsw)];
        s = __builtin_amdgcn_mfma_f32_16x16x32_bf16(qf[kk], kf, s, 0, 0, 0);
      }
      int key = kt * 64 + nt * 16 + (l & 15);
#pragma unroll
      for (int r = 0; r < 4; ++r) {
        int q = q0 + w * 16 + (l >> 4) * 4 + r;
        float p = (q == key) ? 0.f : __expf(s[r] * 0.125f);  // diag mask == -1e9
        dsum[r] += p;
        int prow = w * 16 + (l >> 4) * 4 + r;
        Ps[prow * 64 + ((nt * 16 + (l & 15)) ^ ((prow & 7) << 3))] = f2bf(p);
      }
    }
    __syncthreads();

    // O += P * V   (A = P [16 x 64key], B = V [64key x 64d] via V^T tile)
#pragma unroll
    for (int nt = 0; nt < 4; ++nt) {
#pragma unroll
      for (int kk = 0; kk < 2; ++kk) {
        bf16x8 pf = *(const bf16x8*)&Ps[(w * 16 + (l & 15)) * 64 +
                                        ((kk * 32 + (l >> 4) * 8) ^ rsw)];
        bf16x8 vf = *(const bf16x8*)&Vs[(nt * 16 + (l & 15)) * 64 +
                                        ((kk * 32 + (l >> 4) * 8) ^ rsw)];
        o[nt] = __builtin_amdgcn_mfma_f32_16x16x32_bf16(pf, vf, o[nt], 0, 0, 0);
      }
    }
    __syncthreads();
  }

  // row sums: reduce across the 16 "column" lanes (low 4 lane bits)
#pragma unroll
  for (int m = 1; m < 16; m <<= 1)
#pragma unroll
    for (int r = 0; r < 4; ++r)
      dsum[r] += __shfl_xor(dsum[r], m, 64);

  float inv[4];
#pragma unroll
  for (int r = 0; r < 4; ++r) inv[r] = 1.f / dsum[r];

#pragma unroll
  for (int nt = 0; nt < 4; ++nt)
#pragma unroll
    for (int r = 0; r < 4; ++r) {
      int t = q0 + w * 16 + (l >> 4) * 4 + r;
      int cc = h * 64 + nt * 16 + (l & 15);
      Yp[(b * 2048 + t) * 512 + cc] = f2bf(o[nt][r] * inv[r]);
    }
}

// ---------- launch ----------
extern "C" void kernel_launch(void* const* d_in, const int* in_sizes, int n_in,
                              void* d_out, int out_size, void* d_ws, size_t ws_size,
                              hipStream_t stream) {
  const float* x = (const float*)d_in[0];
  const float* wqkv = (const float*)d_in[1];
  const float* wproj = (const float*)d_in[2];
  float* out = (float*)d_out;
  char* ws = (char*)d_ws;

  // workspace layout (peak 36.2 MB):
  //   xb region is reused for Yp (xb dead after GEMM1; Yp written after).
  u16* xb     = (u16*)(ws);                    //  8,388,608 B  (aliased w/ Yp)
  u16* Yp     = (u16*)(ws);                    //  8,388,608 B
  u16* wqkvT  = (u16*)(ws + 8388608);          //  1,572,864
  u16* wprojT = (u16*)(ws + 9961472);          //    524,288
  u16* Qp     = (u16*)(ws + 10485760);         //  8,388,608
  u16* Kp     = (u16*)(ws + 18874368);         //  8,388,608
  u16* VTp    = (u16*)(ws + 27262976);         //  8,388,608
  float* cosT = (float*)(ws + 35651584);       //    262,144
  float* sinT = (float*)(ws + 35913728);       //    262,144

  cast4_kernel<<<4096, 256, 0, stream>>>(x, xb);                       // 4 M floats /4
  castT_kernel<<<3072, 256, 0, stream>>>(wqkv, wqkvT, 512, 1536);
  castT_kernel<<<1024, 256, 0, stream>>>(wproj, wprojT, 512, 512);
  rope_table_kernel<<<256, 256, 0, stream>>>(cosT, sinT);

  gemm_bt_kernel<0><<<dim3(64, 12), 256, 0, stream>>>(xb, wqkvT, 8192, 1536, 512,
                                                      nullptr, Qp, Kp, VTp);
  rope_kernel<<<16384, 256, 0, stream>>>(Qp, Kp, cosT, sinT);
  attn_kernel<<<dim3(32, 32), 256, 0, stream>>>(Qp, Kp, VTp, Yp);
  gemm_bt_kernel<1><<<dim3(64, 4), 256, 0, stream>>>(Yp, wprojT, 8192, 512, 512,
                                                     out, nullptr, nullptr, nullptr);
}

// Round 9
// 194.801 us; speedup vs baseline: 1.0229x; 1.0229x over previous
//
#include <hip/hip_runtime.h>

typedef unsigned short u16;
typedef __bf16 bf16x8 __attribute__((ext_vector_type(8)));
typedef float f32x4 __attribute__((ext_vector_type(4)));

#define B_ 4
#define T_ 2048
#define C_ 512
#define H_ 8
#define D_ 64

// ---------- helpers ----------
__device__ __forceinline__ u16 f2bf(float f) {
  unsigned u = __float_as_uint(f);
  unsigned r = (u + 0x7FFFu + ((u >> 16) & 1u)) >> 16;
  return (u16)r;
}
__device__ __forceinline__ float bf2f(unsigned h) {
  return __uint_as_float(h << 16);
}
__device__ __forceinline__ void gload16(const u16* g, u16* l) {
  __builtin_amdgcn_global_load_lds(
      (const __attribute__((address_space(1))) unsigned int*)g,
      (__attribute__((address_space(3))) unsigned int*)l, 16, 0, 0);
}

// ---------- cast kernels ----------
__global__ void cast4_kernel(const float* __restrict__ in, u16* __restrict__ out) {
  int i = blockIdx.x * blockDim.x + threadIdx.x;   // over float4s (exact grid)
  float4 v = ((const float4*)in)[i];
  unsigned lo = (unsigned)f2bf(v.x) | ((unsigned)f2bf(v.y) << 16);
  unsigned hi = (unsigned)f2bf(v.z) | ((unsigned)f2bf(v.w) << 16);
  ((uint2*)out)[i] = make_uint2(lo, hi);
}

// transpose-cast, indexed by OUTPUT element: writes coalesced, strided reads L2-cached.
__global__ void castT_kernel(const float* __restrict__ in, u16* __restrict__ outT,
                             int R, int Cc) {
  int i = blockIdx.x * blockDim.x + threadIdx.x;   // over outT elements (Cc x R)
  if (i >= R * Cc) return;
  int c = i / R, r = i - c * R;
  outT[i] = f2bf(in[r * Cc + c]);
}

// ---------- RoPE ----------
__global__ void rope_table_kernel(float* __restrict__ cosT, float* __restrict__ sinT) {
  int i = blockIdx.x * blockDim.x + threadIdx.x;   // 65536 = T*32 exact
  int t = i >> 5, p = i & 31;
  float theta = powf(10000.f, -(float)p / 32.f);
  float a = (float)t * theta;
  cosT[i] = cosf(a);
  sinT[i] = sinf(a);
}

__global__ void rope_kernel(u16* __restrict__ Qp, u16* __restrict__ Kp,
                            const float* __restrict__ cosT, const float* __restrict__ sinT) {
  int i = blockIdx.x * blockDim.x + threadIdx.x;   // 4,194,304 exact
  int p = i & 31;
  int t = (i >> 5) & 2047;
  int bh = (i >> 16) & 31;
  u16* base = (i >> 21) ? Kp : Qp;
  unsigned off = ((unsigned)(bh * 2048 + t)) * 64u + (unsigned)(p * 2);
  unsigned v = *(const unsigned*)&base[off];
  int ti = (t << 5) + p;
  float c = cosT[ti], s = sinT[ti];
  float x1 = bf2f(v & 0xFFFFu), x2 = bf2f(v >> 16);
  float o1 = x1 * c - x2 * s;
  float o2 = x1 * s + x2 * c;
  *(unsigned*)&base[off] = (unsigned)f2bf(o1) | ((unsigned)f2bf(o2) << 16);
}

// ---------- GEMM: C = A * B, B given transposed (BT is N x K), all bf16, fp32 acc ----------
// (unswizzled: 2-phase structure, T2 is regime-gated null here per m252)
// EPI 0: scatter epilogue -> Q, K (bf16 [BH,T,D]) and VT (bf16 [BH,D,T])
// EPI 1: plain fp32 store to Cout (M x N)
template <int EPI>
__global__ __launch_bounds__(256, 2)
void gemm_bt_kernel(const u16* __restrict__ A, const u16* __restrict__ BT,
                    int M, int N, int K, float* __restrict__ Cout,
                    u16* __restrict__ Qp, u16* __restrict__ Kp, u16* __restrict__ VTp) {
  __shared__ u16 As[128 * 64];
  __shared__ u16 Bs[128 * 64];
  const int tid = threadIdx.x;
  const int w = tid >> 6, l = tid & 63;
  const int m0 = blockIdx.x * 128, n0 = blockIdx.y * 128;
  const int wr = w >> 1, wc = w & 1;
  f32x4 acc[4][4] = {};

  const int srow = w * 32 + (l >> 3);  // +c*8
  const int scol = (l & 7) * 8;

  for (int k0 = 0; k0 < K; k0 += 64) {
#pragma unroll
    for (int c = 0; c < 4; ++c) {
      gload16(A + (m0 + srow + c * 8) * K + k0 + scol, &As[(w * 32 + c * 8) * 64]);
      gload16(BT + (n0 + srow + c * 8) * K + k0 + scol, &Bs[(w * 32 + c * 8) * 64]);
    }
    __syncthreads();
#pragma unroll
    for (int kk = 0; kk < 2; ++kk) {
      bf16x8 af[4], bfr[4];
#pragma unroll
      for (int i = 0; i < 4; ++i)
        af[i] = *(const bf16x8*)&As[(wr * 64 + i * 16 + (l & 15)) * 64 + kk * 32 + (l >> 4) * 8];
#pragma unroll
      for (int j = 0; j < 4; ++j)
        bfr[j] = *(const bf16x8*)&Bs[(wc * 64 + j * 16 + (l & 15)) * 64 + kk * 32 + (l >> 4) * 8];
#pragma unroll
      for (int i = 0; i < 4; ++i)
#pragma unroll
        for (int j = 0; j < 4; ++j)
          acc[i][j] = __builtin_amdgcn_mfma_f32_16x16x32_bf16(af[i], bfr[j], acc[i][j], 0, 0, 0);
    }
    __syncthreads();
  }

  const int mrow = wr * 64 + (l >> 4) * 4;
  const int ncol = wc * 64 + (l & 15);
  if (EPI == 1) {
#pragma unroll
    for (int i = 0; i < 4; ++i)
#pragma unroll
      for (int j = 0; j < 4; ++j)
#pragma unroll
        for (int r = 0; r < 4; ++r)
          Cout[(m0 + mrow + i * 16 + r) * N + (n0 + ncol + j * 16)] = acc[i][j][r];
  } else {
#pragma unroll
    for (int i = 0; i < 4; ++i) {
#pragma unroll
      for (int j = 0; j < 4; ++j) {
        int n = n0 + ncol + j * 16;
        int which = n >> 9;
        int hn = n & 511;
        int h = hn >> 6, d = hn & 63;
#pragma unroll
        for (int r = 0; r < 4; ++r) {
          int m = m0 + mrow + i * 16 + r;
          int b = m >> 11, t = m & 2047;
          int bh = b * 8 + h;
          u16 v = f2bf(acc[i][j][r]);
          if (which == 0)
            Qp[(bh * 2048 + t) * 64 + d] = v;
          else if (which == 1)
            Kp[(bh * 2048 + t) * 64 + d] = v;
          else
            VTp[(bh * 64 + d) * 2048 + t] = v;
        }
      }
    }
  }
}

// ---------- attention: per block one (b,h) and 64 q rows; 4 waves x 16 q rows ----------
// T2 XOR-swizzle on Ks/Vs/Ps (lds(row,col) = data(row, col^((row&7)<<3)); linear lds
// dest + pre-swizzled global source, rule #21).
// T3-min double-buffer: STAGE(kt+1) issued before compute(kt); ONE barrier/tile
// (P round-trip is intra-wave: each wave writes/reads only its own 16 Ps rows).
__global__ __launch_bounds__(256, 2)
void attn_kernel(const u16* __restrict__ Qp, const u16* __restrict__ Kp,
                 const u16* __restrict__ VTp, u16* __restrict__ Yp) {
  __shared__ u16 Ks[2][64 * 64];   // [buf][key][d], swizzled
  __shared__ u16 Vs[2][64 * 64];   // [buf][d][key]  (V^T tile), swizzled
  __shared__ u16 Ps[4 * 16 * 64];  // swizzled, per-wave private rows
  const int tid = threadIdx.x;
  const int w = tid >> 6, l = tid & 63;
  const int qt = blockIdx.x, bh = blockIdx.y;
  const int b = bh >> 3, h = bh & 7;
  const int q0 = qt * 64;
  const u16* Qb = Qp + (bh * 2048 + q0) * 64;
  const u16* Kb = Kp + bh * 2048 * 64;
  const u16* Vb = VTp + bh * 64 * 2048;

  // hoist Q fragments (16 rows per wave, D=64 over 2 k-steps) — global, unswizzled
  bf16x8 qf[2];
  {
    int row = w * 16 + (l & 15);
#pragma unroll
    for (int kk = 0; kk < 2; ++kk)
      qf[kk] = *(const bf16x8*)&Qb[row * 64 + kk * 32 + (l >> 4) * 8];
  }
  f32x4 o[4] = {};
  float dsum[4] = {0.f, 0.f, 0.f, 0.f};

  const int srow = w * 16 + (l >> 3);                 // +c*8; (row&7) == l>>3
  const int scol = ((l & 7) ^ (l >> 3)) * 8;          // pre-swizzled source col
  const int rsw  = (l & 7) << 3;                      // read-side XOR (row&7 == l&7)

  // stage tile kt into buffer bb (linear LDS dest, swizzled global col)
#define STAGE(kt, bb)                                                            \
  do {                                                                           \
    _Pragma("unroll")                                                            \
    for (int c = 0; c < 2; ++c) {                                                \
      gload16(Kb + ((kt) * 64 + srow + c * 8) * 64 + scol,                       \
              &Ks[bb][(w * 16 + c * 8) * 64]);                                   \
      gload16(Vb + (srow + c * 8) * 2048 + (kt) * 64 + scol,                     \
              &Vs[bb][(w * 16 + c * 8) * 64]);                                   \
    }                                                                            \
  } while (0)

  STAGE(0, 0);
  __syncthreads();   // drains vmcnt(0) + barrier (hipcc __syncthreads semantics)

  int cur = 0;
  for (int kt = 0; kt < 32; ++kt) {
    if (kt < 31) STAGE(kt + 1, cur ^ 1);   // prefetch next tile, hidden under compute
    const bool diagtile = (kt == qt);

    // S = Q K^T for this wave's 16 q rows x 64 keys
#pragma unroll
    for (int nt = 0; nt < 4; ++nt) {
      f32x4 s = {0.f, 0.f, 0.f, 0.f};
#pragma unroll
      for (int kk = 0; kk < 2; ++kk) {
        bf16x8 kf = *(const bf16x8*)&Ks[cur][(nt * 16 + (l & 15)) * 64 +
                                           ((kk * 32 + (l >> 4) * 8) ^ rsw)];
        s = __builtin_amdgcn_mfma_f32_16x16x32_bf16(qf[kk], kf, s, 0, 0, 0);
      }
      int keyi = nt * 16 + (l & 15);       // key index within tile
#pragma unroll
      for (int r = 0; r < 4; ++r) {
        int qrow = w * 16 + (l >> 4) * 4 + r;   // q index within tile
        float e = __expf(s[r] * 0.125f);
        if (diagtile && (qrow == keyi)) e = 0.f;   // diag mask == -1e9
        dsum[r] += e;
        Ps[qrow * 64 + (keyi ^ ((qrow & 7) << 3))] = f2bf(e);
      }
    }
    // no barrier: Ps rows are wave-private; compiler inserts lgkmcnt for the RAW dep

    // O += P * V   (A = P [16 x 64key], B = V [64key x 64d] via V^T tile)
#pragma unroll
    for (int nt = 0; nt < 4; ++nt) {
#pragma unroll
      for (int kk = 0; kk < 2; ++kk) {
        bf16x8 pf = *(const bf16x8*)&Ps[(w * 16 + (l & 15)) * 64 +
                                        ((kk * 32 + (l >> 4) * 8) ^ rsw)];
        bf16x8 vf = *(const bf16x8*)&Vs[cur][(nt * 16 + (l & 15)) * 64 +
                                            ((kk * 32 + (l >> 4) * 8) ^ rsw)];
        o[nt] = __builtin_amdgcn_mfma_f32_16x16x32_bf16(pf, vf, o[nt], 0, 0, 0);
      }
    }
    __syncthreads();   // drains prefetch vmcnt(0); protects buf reuse next iter
    cur ^= 1;
  }
#undef STAGE

  // row sums: reduce across the 16 "column" lanes (low 4 lane bits)
#pragma unroll
  for (int m = 1; m < 16; m <<= 1)
#pragma unroll
    for (int r = 0; r < 4; ++r)
      dsum[r] += __shfl_xor(dsum[r], m, 64);

  float inv[4];
#pragma unroll
  for (int r = 0; r < 4; ++r) inv[r] = 1.f / dsum[r];

#pragma unroll
  for (int nt = 0; nt < 4; ++nt)
#pragma unroll
    for (int r = 0; r < 4; ++r) {
      int t = q0 + w * 16 + (l >> 4) * 4 + r;
      int cc = h * 64 + nt * 16 + (l & 15);
      Yp[(b * 2048 + t) * 512 + cc] = f2bf(o[nt][r] * inv[r]);
    }
}

// ---------- launch ----------
extern "C" void kernel_launch(void* const* d_in, const int* in_sizes, int n_in,
                              void* d_out, int out_size, void* d_ws, size_t ws_size,
                              hipStream_t stream) {
  const float* x = (const float*)d_in[0];
  const float* wqkv = (const float*)d_in[1];
  const float* wproj = (const float*)d_in[2];
  float* out = (float*)d_out;
  char* ws = (char*)d_ws;

  // workspace layout (peak 36.2 MB):
  //   xb region is reused for Yp (xb dead after GEMM1; Yp written after).
  u16* xb     = (u16*)(ws);                    //  8,388,608 B  (aliased w/ Yp)
  u16* Yp     = (u16*)(ws);                    //  8,388,608 B
  u16* wqkvT  = (u16*)(ws + 8388608);          //  1,572,864
  u16* wprojT = (u16*)(ws + 9961472);          //    524,288
  u16* Qp     = (u16*)(ws + 10485760);         //  8,388,608
  u16* Kp     = (u16*)(ws + 18874368);         //  8,388,608
  u16* VTp    = (u16*)(ws + 27262976);         //  8,388,608
  float* cosT = (float*)(ws + 35651584);       //    262,144
  float* sinT = (float*)(ws + 35913728);       //    262,144

  cast4_kernel<<<4096, 256, 0, stream>>>(x, xb);                       // 4 M floats /4
  castT_kernel<<<3072, 256, 0, stream>>>(wqkv, wqkvT, 512, 1536);
  castT_kernel<<<1024, 256, 0, stream>>>(wproj, wprojT, 512, 512);
  rope_table_kernel<<<256, 256, 0, stream>>>(cosT, sinT);

  gemm_bt_kernel<0><<<dim3(64, 12), 256, 0, stream>>>(xb, wqkvT, 8192, 1536, 512,
                                                      nullptr, Qp, Kp, VTp);
  rope_kernel<<<16384, 256, 0, stream>>>(Qp, Kp, cosT, sinT);
  attn_kernel<<<dim3(32, 32), 256, 0, stream>>>(Qp, Kp, VTp, Yp);
  gemm_bt_kernel<1><<<dim3(64, 4), 256, 0, stream>>>(Yp, wprojT, 8192, 512, 512,
                                                     out, nullptr, nullptr, nullptr);
}

// Round 12
// 189.353 us; speedup vs baseline: 1.0524x; 1.0288x over previous
//
#include <hip/hip_runtime.h>

typedef unsigned short u16;
typedef __bf16 bf16x8 __attribute__((ext_vector_type(8)));
typedef float f32x4 __attribute__((ext_vector_type(4)));

#define B_ 4
#define T_ 2048
#define C_ 512
#define H_ 8
#define D_ 64

// ---------- helpers ----------
__device__ __forceinline__ u16 f2bf(float f) {
  unsigned u = __float_as_uint(f);
  unsigned r = (u + 0x7FFFu + ((u >> 16) & 1u)) >> 16;
  return (u16)r;
}
__device__ __forceinline__ float bf2f(unsigned h) {
  return __uint_as_float(h << 16);
}
// single v_exp_f32 (exp2) via compiler-managed intrinsic: the compiler inserts
// the required trans-op hazard wait states (raw inline asm did NOT -> r9 bug).
__device__ __forceinline__ float exp2_fast(float x) {
#if __has_builtin(__builtin_amdgcn_exp2f)
  return __builtin_amdgcn_exp2f(x);
#else
  return exp2f(x);
#endif
}
__device__ __forceinline__ void gload16(const u16* g, u16* l) {
  __builtin_amdgcn_global_load_lds(
      (const __attribute__((address_space(1))) unsigned int*)g,
      (__attribute__((address_space(3))) unsigned int*)l, 16, 0, 0);
}

// ---------- cast kernels ----------
__global__ void cast4_kernel(const float* __restrict__ in, u16* __restrict__ out) {
  int i = blockIdx.x * blockDim.x + threadIdx.x;   // over float4s (exact grid)
  float4 v = ((const float4*)in)[i];
  unsigned lo = (unsigned)f2bf(v.x) | ((unsigned)f2bf(v.y) << 16);
  unsigned hi = (unsigned)f2bf(v.z) | ((unsigned)f2bf(v.w) << 16);
  ((uint2*)out)[i] = make_uint2(lo, hi);
}

// transpose-cast, indexed by OUTPUT element: writes coalesced, strided reads L2-cached.
__global__ void castT_kernel(const float* __restrict__ in, u16* __restrict__ outT,
                             int R, int Cc) {
  int i = blockIdx.x * blockDim.x + threadIdx.x;   // over outT elements (Cc x R)
  if (i >= R * Cc) return;
  int c = i / R, r = i - c * R;
  outT[i] = f2bf(in[r * Cc + c]);
}

// ---------- RoPE ----------
__global__ void rope_table_kernel(float* __restrict__ cosT, float* __restrict__ sinT) {
  int i = blockIdx.x * blockDim.x + threadIdx.x;   // 65536 = T*32 exact
  int t = i >> 5, p = i & 31;
  float theta = powf(10000.f, -(float)p / 32.f);
  float a = (float)t * theta;
  cosT[i] = cosf(a);
  sinT[i] = sinf(a);
}

// Q outputs are pre-scaled by 0.125*log2(e) so attn can use a raw exp2
// with no per-element multiply: exp2(q'.k) == exp(0.125*q.k).
__global__ void rope_kernel(u16* __restrict__ Qp, u16* __restrict__ Kp,
                            const float* __restrict__ cosT, const float* __restrict__ sinT) {
  int i = blockIdx.x * blockDim.x + threadIdx.x;   // 4,194,304 exact
  int p = i & 31;
  int t = (i >> 5) & 2047;
  int bh = (i >> 16) & 31;
  bool isK = (i >> 21) != 0;
  u16* base = isK ? Kp : Qp;
  unsigned off = ((unsigned)(bh * 2048 + t)) * 64u + (unsigned)(p * 2);
  unsigned v = *(const unsigned*)&base[off];
  int ti = (t << 5) + p;
  float c = cosT[ti], s = sinT[ti];
  float x1 = bf2f(v & 0xFFFFu), x2 = bf2f(v >> 16);
  float sc = isK ? 1.0f : 0.18033688011f;   // 0.125 * log2(e)
  float o1 = (x1 * c - x2 * s) * sc;
  float o2 = (x1 * s + x2 * c) * sc;
  *(unsigned*)&base[off] = (unsigned)f2bf(o1) | ((unsigned)f2bf(o2) << 16);
}

// ---------- GEMM: C = A * B, B given transposed (BT is N x K), all bf16, fp32 acc ----------
// EPI 0: scatter epilogue -> Q, K (bf16 [BH,T,D]) and VT (bf16 [BH,D,T], packed b64)
// EPI 1: plain fp32 store to Cout (M x N)
template <int EPI>
__global__ __launch_bounds__(256, 2)
void gemm_bt_kernel(const u16* __restrict__ A, const u16* __restrict__ BT,
                    int M, int N, int K, float* __restrict__ Cout,
                    u16* __restrict__ Qp, u16* __restrict__ Kp, u16* __restrict__ VTp) {
  __shared__ u16 As[128 * 64];
  __shared__ u16 Bs[128 * 64];
  const int tid = threadIdx.x;
  const int w = tid >> 6, l = tid & 63;
  const int m0 = blockIdx.x * 128, n0 = blockIdx.y * 128;
  const int wr = w >> 1, wc = w & 1;
  f32x4 acc[4][4] = {};

  const int srow = w * 32 + (l >> 3);  // +c*8
  const int scol = (l & 7) * 8;

  for (int k0 = 0; k0 < K; k0 += 64) {
#pragma unroll
    for (int c = 0; c < 4; ++c) {
      gload16(A + (m0 + srow + c * 8) * K + k0 + scol, &As[(w * 32 + c * 8) * 64]);
      gload16(BT + (n0 + srow + c * 8) * K + k0 + scol, &Bs[(w * 32 + c * 8) * 64]);
    }
    __syncthreads();
#pragma unroll
    for (int kk = 0; kk < 2; ++kk) {
      bf16x8 af[4], bfr[4];
#pragma unroll
      for (int i = 0; i < 4; ++i)
        af[i] = *(const bf16x8*)&As[(wr * 64 + i * 16 + (l & 15)) * 64 + kk * 32 + (l >> 4) * 8];
#pragma unroll
      for (int j = 0; j < 4; ++j)
        bfr[j] = *(const bf16x8*)&Bs[(wc * 64 + j * 16 + (l & 15)) * 64 + kk * 32 + (l >> 4) * 8];
#pragma unroll
      for (int i = 0; i < 4; ++i)
#pragma unroll
        for (int j = 0; j < 4; ++j)
          acc[i][j] = __builtin_amdgcn_mfma_f32_16x16x32_bf16(af[i], bfr[j], acc[i][j], 0, 0, 0);
    }
    __syncthreads();
  }

  const int mrow = wr * 64 + (l >> 4) * 4;
  const int ncol = wc * 64 + (l & 15);
  if (EPI == 1) {
#pragma unroll
    for (int i = 0; i < 4; ++i)
#pragma unroll
      for (int j = 0; j < 4; ++j)
#pragma unroll
        for (int r = 0; r < 4; ++r)
          Cout[(m0 + mrow + i * 16 + r) * N + (n0 + ncol + j * 16)] = acc[i][j][r];
  } else {
#pragma unroll
    for (int i = 0; i < 4; ++i) {
#pragma unroll
      for (int j = 0; j < 4; ++j) {
        int n = n0 + ncol + j * 16;
        int which = n >> 9;          // uniform per block (128-wide n-range)
        int hn = n & 511;
        int h = hn >> 6, d = hn & 63;
        if (which == 2) {
          // VT: r=0..3 are consecutive t at fixed (bh,d) -> one 8B store
          int m_ = m0 + mrow + i * 16;
          int b_ = m_ >> 11, t_ = m_ & 2047;
          int bh_ = b_ * 8 + h;
          unsigned v01 = (unsigned)f2bf(acc[i][j][0]) | ((unsigned)f2bf(acc[i][j][1]) << 16);
          unsigned v23 = (unsigned)f2bf(acc[i][j][2]) | ((unsigned)f2bf(acc[i][j][3]) << 16);
          *(uint2*)&VTp[(bh_ * 64 + d) * 2048 + t_] = make_uint2(v01, v23);
        } else {
#pragma unroll
          for (int r = 0; r < 4; ++r) {
            int m = m0 + mrow + i * 16 + r;
            int b = m >> 11, t = m & 2047;
            int bh = b * 8 + h;
            u16 v = f2bf(acc[i][j][r]);
            if (which == 0)
              Qp[(bh * 2048 + t) * 64 + d] = v;
            else
              Kp[(bh * 2048 + t) * 64 + d] = v;
          }
        }
      }
    }
  }
}

// ---------- attention: per block one (b,h) and 64 q rows; 4 waves x 16 q rows ----------
// T2 XOR-swizzle on Ks/Vs/Ps (lds(row,col) = data(row, col^((row&7)<<3)); linear lds
// dest + pre-swizzled global source, rule #21).
// Double-buffered staging, ONE barrier/tile (Ps rows are wave-private).
// Softmax: Q pre-scaled in rope -> e = exp2_fast(s); diag mask on wave-uniform
// kt==qt branch only.
__global__ __launch_bounds__(256, 2)
void attn_kernel(const u16* __restrict__ Qp, const u16* __restrict__ Kp,
                 const u16* __restrict__ VTp, u16* __restrict__ Yp) {
  __shared__ u16 Ks[2][64 * 64];   // [buf][key][d], swizzled
  __shared__ u16 Vs[2][64 * 64];   // [buf][d][key]  (V^T tile), swizzled
  __shared__ u16 Ps[4 * 16 * 64];  // swizzled, per-wave private rows
  const int tid = threadIdx.x;
  const int w = tid >> 6, l = tid & 63;
  const int qt = blockIdx.x, bh = blockIdx.y;
  const int b = bh >> 3, h = bh & 7;
  const int q0 = qt * 64;
  const u16* Qb = Qp + (bh * 2048 + q0) * 64;
  const u16* Kb = Kp + bh * 2048 * 64;
  const u16* Vb = VTp + bh * 64 * 2048;

  // hoist Q fragments (16 rows per wave, D=64 over 2 k-steps) — global, unswizzled
  bf16x8 qf[2];
  {
    int row = w * 16 + (l & 15);
#pragma unroll
    for (int kk = 0; kk < 2; ++kk)
      qf[kk] = *(const bf16x8*)&Qb[row * 64 + kk * 32 + (l >> 4) * 8];
  }
  f32x4 o[4] = {};
  float dsum[4] = {0.f, 0.f, 0.f, 0.f};

  const int srow = w * 16 + (l >> 3);                 // +c*8; (row&7) == l>>3
  const int scol = ((l & 7) ^ (l >> 3)) * 8;          // pre-swizzled source col
  const int rsw  = (l & 7) << 3;                      // read-side XOR (row&7 == l&7)

  // stage tile kt into buffer bb (linear LDS dest, swizzled global col)
#define STAGE(kt, bb)                                                            \
  do {                                                                           \
    _Pragma("unroll")                                                            \
    for (int c = 0; c < 2; ++c) {                                                \
      gload16(Kb + ((kt) * 64 + srow + c * 8) * 64 + scol,                       \
              &Ks[bb][(w * 16 + c * 8) * 64]);                                   \
      gload16(Vb + (srow + c * 8) * 2048 + (kt) * 64 + scol,                     \
              &Vs[bb][(w * 16 + c * 8) * 64]);                                   \
    }                                                                            \
  } while (0)

  STAGE(0, 0);
  __syncthreads();   // drains vmcnt(0) + barrier (hipcc __syncthreads semantics)

  int cur = 0;
  for (int kt = 0; kt < 32; ++kt) {
    if (kt < 31) STAGE(kt + 1, cur ^ 1);   // prefetch next tile, hidden under compute

    // S = Q K^T for this wave's 16 q rows x 64 keys
#pragma unroll
    for (int nt = 0; nt < 4; ++nt) {
      f32x4 s = {0.f, 0.f, 0.f, 0.f};
#pragma unroll
      for (int kk = 0; kk < 2; ++kk) {
        bf16x8 kf = *(const bf16x8*)&Ks[cur][(nt * 16 + (l & 15)) * 64 +
                                           ((kk * 32 + (l >> 4) * 8) ^ rsw)];
        s = __builtin_amdgcn_mfma_f32_16x16x32_bf16(qf[kk], kf, s, 0, 0, 0);
      }
      int keyi = nt * 16 + (l & 15);       // key index within tile
      if (kt == qt) {                       // wave-uniform: diagonal tile (1 of 32)
#pragma unroll
        for (int r = 0; r < 4; ++r) {
          int qrow = w * 16 + (l >> 4) * 4 + r;
          float e = exp2_fast(s[r]);
          if (qrow == keyi) e = 0.f;       // diag mask == -1e9
          dsum[r] += e;
          Ps[qrow * 64 + (keyi ^ ((qrow & 7) << 3))] = f2bf(e);
        }
      } else {
#pragma unroll
        for (int r = 0; r < 4; ++r) {
          int qrow = w * 16 + (l >> 4) * 4 + r;
          float e = exp2_fast(s[r]);
          dsum[r] += e;
          Ps[qrow * 64 + (keyi ^ ((qrow & 7) << 3))] = f2bf(e);
        }
      }
    }
    // no barrier: Ps rows are wave-private; compiler inserts lgkmcnt for the RAW dep

    // O += P * V   (A = P [16 x 64key], B = V [64key x 64d] via V^T tile)
#pragma unroll
    for (int nt = 0; nt < 4; ++nt) {
#pragma unroll
      for (int kk = 0; kk < 2; ++kk) {
        bf16x8 pf = *(const bf16x8*)&Ps[(w * 16 + (l & 15)) * 64 +
                                        ((kk * 32 + (l >> 4) * 8) ^ rsw)];
        bf16x8 vf = *(const bf16x8*)&Vs[cur][(nt * 16 + (l & 15)) * 64 +
                                            ((kk * 32 + (l >> 4) * 8) ^ rsw)];
        o[nt] = __builtin_amdgcn_mfma_f32_16x16x32_bf16(pf, vf, o[nt], 0, 0, 0);
      }
    }
    __syncthreads();   // drains prefetch vmcnt(0); protects buf reuse next iter
    cur ^= 1;
  }
#undef STAGE

  // row sums: reduce across the 16 "column" lanes (low 4 lane bits)
#pragma unroll
  for (int m = 1; m < 16; m <<= 1)
#pragma unroll
    for (int r = 0; r < 4; ++r)
      dsum[r] += __shfl_xor(dsum[r], m, 64);

  float inv[4];
#pragma unroll
  for (int r = 0; r < 4; ++r) inv[r] = 1.f / dsum[r];

#pragma unroll
  for (int nt = 0; nt < 4; ++nt)
#pragma unroll
    for (int r = 0; r < 4; ++r) {
      int t = q0 + w * 16 + (l >> 4) * 4 + r;
      int cc = h * 64 + nt * 16 + (l & 15);
      Yp[(b * 2048 + t) * 512 + cc] = f2bf(o[nt][r] * inv[r]);
    }
}

// ---------- launch ----------
extern "C" void kernel_launch(void* const* d_in, const int* in_sizes, int n_in,
                              void* d_out, int out_size, void* d_ws, size_t ws_size,
                              hipStream_t stream) {
  const float* x = (const float*)d_in[0];
  const float* wqkv = (const float*)d_in[1];
  const float* wproj = (const float*)d_in[2];
  float* out = (float*)d_out;
  char* ws = (char*)d_ws;

  // workspace layout (peak 36.2 MB):
  //   xb region is reused for Yp (xb dead after GEMM1; Yp written after).
  u16* xb     = (u16*)(ws);                    //  8,388,608 B  (aliased w/ Yp)
  u16* Yp     = (u16*)(ws);                    //  8,388,608 B
  u16* wqkvT  = (u16*)(ws + 8388608);          //  1,572,864
  u16* wprojT = (u16*)(ws + 9961472);          //    524,288
  u16* Qp     = (u16*)(ws + 10485760);         //  8,388,608
  u16* Kp     = (u16*)(ws + 18874368);         //  8,388,608
  u16* VTp    = (u16*)(ws + 27262976);         //  8,388,608
  float* cosT = (float*)(ws + 35651584);       //    262,144
  float* sinT = (float*)(ws + 35913728);       //    262,144

  cast4_kernel<<<4096, 256, 0, stream>>>(x, xb);                       // 4 M floats /4
  castT_kernel<<<3072, 256, 0, stream>>>(wqkv, wqkvT, 512, 1536);
  castT_kernel<<<1024, 256, 0, stream>>>(wproj, wprojT, 512, 512);
  rope_table_kernel<<<256, 256, 0, stream>>>(cosT, sinT);

  gemm_bt_kernel<0><<<dim3(64, 12), 256, 0, stream>>>(xb, wqkvT, 8192, 1536, 512,
                                                      nullptr, Qp, Kp, VTp);
  rope_kernel<<<16384, 256, 0, stream>>>(Qp, Kp, cosT, sinT);
  attn_kernel<<<dim3(32, 32), 256, 0, stream>>>(Qp, Kp, VTp, Yp);
  gemm_bt_kernel<1><<<dim3(64, 4), 256, 0, stream>>>(Yp, wprojT, 8192, 512, 512,
                                                     out, nullptr, nullptr, nullptr);
}